// Round 5
// baseline (582.385 us; speedup 1.0000x reference)
//
#include <hip/hip_runtime.h>
#include <math.h>

#define BATCH 32

// ---------------------------------------------------------------- utilities
__device__ __forceinline__ float eluf(float v) { return v > 0.f ? v : expm1f(v); }
__device__ __forceinline__ float softplusf(float x) {
    return fmaxf(x, 0.f) + log1pf(expf(-fabsf(x)));
}
__device__ __forceinline__ float sigmoidf(float x) { return 1.f / (1.f + expf(-x)); }

// ---------------------------------------------------------------- fused conv 3x3 stride 2
// Block = (b, co-group of 8, y-strip of ROWS output rows). Thread = 1 output px x 8 co.
// Input strip is staged into LDS in CHUNK-channel slices; if DO_BN, the previous
// layer's BN+ELU (from its raw stats) is applied during staging, so h-buffers hold
// RAW conv outputs and the separate bnelu pass disappears.
// Epilogue: per-channel sum/sumsq of this layer's raw output -> stats (atomics).
template <int CIN, int HIN, int WIN, int HOUT, int WOUT, int ROWS, int BLOCK, int CHUNK, bool DO_BN>
__global__ __launch_bounds__(BLOCK, 2) void conv_kernel(
    const float* __restrict__ in, const float* __restrict__ w, const float* __restrict__ bias,
    const float* __restrict__ prev_stats, const float* __restrict__ g, const float* __restrict__ be,
    float* __restrict__ out, float* __restrict__ stats)
{
    constexpr int TROWS = 2 * ROWS + 1;
    constexpr int WPAD  = (WIN % 2 == 0) ? WIN + 1 : WIN;  // odd stride breaks bank aliasing
    constexpr int NW    = BLOCK / 64;

    __shared__ float tile[CHUNK * TROWS * WPAD];
    __shared__ float bn_a[DO_BN ? CIN : 1];
    __shared__ float bn_b[DO_BN ? CIN : 1];
    __shared__ float red_s[NW][8];
    __shared__ float red_q[NW][8];

    const int b   = blockIdx.x;
    const int co0 = blockIdx.y * 8;
    const int y0  = blockIdx.z * ROWS;
    const int t   = threadIdx.x;

    if (DO_BN) {
        if (t < CIN) {
            constexpr float invN = 1.f / (float)(BATCH * HIN * WIN);
            float s = prev_stats[2 * t], q = prev_stats[2 * t + 1];
            float m = s * invN;
            float var = fmaf(q, invN, -m * m);
            float a = g[t] * rsqrtf(var + 1e-5f);
            bn_a[t] = a;
            bn_b[t] = fmaf(-a, m, be[t]);
        }
        __syncthreads();
    }

    const int ly_r = t / WOUT;
    const int x_r  = t % WOUT;
    const bool active = (ly_r < ROWS) && (y0 + ly_r < HOUT);
    const int ly = active ? ly_r : 0;   // clamp so inactive threads stay in-bounds in LDS
    const int x  = active ? x_r : 0;
    const int y  = y0 + ly;

    float acc[8];
#pragma unroll
    for (int u = 0; u < 8; ++u) acc[u] = bias[co0 + u];

#pragma unroll 1
    for (int ci0 = 0; ci0 < CIN; ci0 += CHUNK) {
        // ---- stage CHUNK input channels (rows 2*y0 .. 2*y0+TROWS-1) into LDS
#pragma unroll 1
        for (int cc = 0; cc < CHUNK; ++cc) {
            const int ci = ci0 + cc;
            const float* gsrc = in + ((size_t)b * CIN + ci) * (HIN * WIN);
            float a_s = 0.f, b_s = 0.f;
            if (DO_BN) { a_s = bn_a[ci]; b_s = bn_b[ci]; }
            for (int i = t; i < TROWS * WIN; i += BLOCK) {
                const int r = i / WIN, c = i % WIN;
                const int gr = 2 * y0 + r;
                float v = 0.f;
                if (gr < HIN) v = gsrc[gr * WIN + c];
                if (DO_BN) v = eluf(fmaf(a_s, v, b_s));
                tile[(cc * TROWS + r) * WPAD + c] = v;
            }
        }
        __syncthreads();
        // ---- compute from LDS
#pragma unroll
        for (int cc = 0; cc < CHUNK; ++cc) {
            const float* trow = &tile[(cc * TROWS + 2 * ly) * WPAD + 2 * x];
            float pch[9];
#pragma unroll
            for (int ky = 0; ky < 3; ++ky)
#pragma unroll
                for (int kx = 0; kx < 3; ++kx)
                    pch[ky * 3 + kx] = trow[ky * WPAD + kx];
            const float* wc = w + ((size_t)co0 * CIN + (ci0 + cc)) * 9;  // block-uniform -> s_load
#pragma unroll
            for (int u = 0; u < 8; ++u)
#pragma unroll
                for (int j = 0; j < 9; ++j)
                    acc[u] = fmaf(pch[j], wc[u * CIN * 9 + j], acc[u]);
        }
        __syncthreads();
    }

    // ---- write raw output + per-channel stats
    const int lane = t & 63, wv = t >> 6;
#pragma unroll
    for (int u = 0; u < 8; ++u) {
        float v = active ? acc[u] : 0.f;
        if (active)
            out[(((size_t)b * 64 + co0 + u) * HOUT + y) * WOUT + x] = v;
        float s = v, q = v * v;
#pragma unroll
        for (int off = 32; off > 0; off >>= 1) {
            s += __shfl_down(s, off);
            q += __shfl_down(q, off);
        }
        if (lane == 0) { red_s[wv][u] = s; red_q[wv][u] = q; }
    }
    __syncthreads();
    if (t < 16) {
        const int u = t >> 1, which = t & 1;
        float tt = 0.f;
#pragma unroll
        for (int k = 0; k < NW; ++k) tt += which ? red_q[k][u] : red_s[k][u];
        atomicAdd(&stats[2 * (co0 + u) + which], tt);
    }
}

// ---------------------------------------------------------------- head: bnelu(h4) + 1x1 convs + params
__global__ __launch_bounds__(256) void head_kernel(
    const float* __restrict__ x4, const float* __restrict__ stats4,
    const float* __restrict__ g4, const float* __restrict__ be4,
    const float* __restrict__ wp, const float* __restrict__ bp,
    const float* __restrict__ wz, const float* __restrict__ bz,
    const float* __restrict__ eps_scale, const float* __restrict__ eps_shift,
    float* __restrict__ params)
{
    __shared__ float xs[64 * 49];
    __shared__ float fe[64 * 49];
    __shared__ float zz[11 * 49];
    __shared__ float ha[64], hb[64];
    const int b = blockIdx.x, t = threadIdx.x;

    if (t < 64) {
        constexpr float invN = 1.f / (float)(BATCH * 49);
        float s = stats4[2 * t], q = stats4[2 * t + 1];
        float m = s * invN;
        float var = fmaf(q, invN, -m * m);
        float a = g4[t] * rsqrtf(var + 1e-5f);
        ha[t] = a;
        hb[t] = fmaf(-a, m, be4[t]);
    }
    __syncthreads();

    for (int i = t; i < 64 * 49; i += 256) {
        int c = i / 49;
        xs[i] = eluf(fmaf(ha[c], x4[(size_t)b * 64 * 49 + i], hb[c]));
    }
    __syncthreads();

    for (int i = t; i < 64 * 49; i += 256) {
        int co = i / 49, p = i % 49;
        float a = bp[co];
        for (int ci = 0; ci < 64; ++ci) a = fmaf(xs[ci * 49 + p], wp[co * 64 + ci], a);
        fe[i] = eluf(a);
    }
    __syncthreads();

    for (int i = t; i < 11 * 49; i += 256) {
        int co = i / 49, p = i % 49;
        float a = bz[co];
        for (int ci = 0; ci < 64; ++ci) a = fmaf(fe[ci * 49 + p], wz[co * 64 + ci], a);
        zz[i] = a;
    }
    __syncthreads();

    if (t < 49) {
        const int i = t / 7, j = t % 7;
        float es0 = eps_scale[((size_t)b * 49 + t) * 2 + 0];
        float es1 = eps_scale[((size_t)b * 49 + t) * 2 + 1];
        float eh0 = eps_shift[((size_t)b * 49 + t) * 2 + 0];
        float eh1 = eps_shift[((size_t)b * 49 + t) * 2 + 1];
        float zs0 = zz[3 * 49 + t] + softplusf(zz[5 * 49 + t]) * es0;
        float zs1 = zz[4 * 49 + t] + softplusf(zz[6 * 49 + t]) * es1;
        float zh0 = zz[7 * 49 + t] + softplusf(zz[9 * 49 + t]) * eh0;
        float zh1 = zz[8 * 49 + t] + softplusf(zz[10 * 49 + t]) * eh1;
        float th = sigmoidf(zs0) * 0.25f;
        float tw = sigmoidf(zs1) * 0.25f;
        float tx = ((float)i / 7.0f + sigmoidf(zh0) / 7.0f) * 2.f - 1.f;
        float ty = ((float)j / 7.0f + sigmoidf(zh1) / 7.0f) * 2.f - 1.f;
        float4* pp = (float4*)params;
        pp[b * 49 + t] = make_float4(th, tw, tx, ty);
    }
}

// ---------------------------------------------------------------- bilinear glimpse sampler
__device__ __forceinline__ float tap(const float* __restrict__ im, int yy, int xx) {
    bool ok = (xx >= 0) & (xx < 128) & (yy >= 0) & (yy < 128);
    int yc = min(max(yy, 0), 127);
    int xc = min(max(xx, 0), 127);
    return ok ? im[yc * 128 + xc] : 0.f;
}

__global__ __launch_bounds__(256) void sampler_kernel(
    const float* __restrict__ img, const float* __restrict__ params,
    float* __restrict__ out)
{
    const int bk = blockIdx.x;       // b*49 + k
    const int b  = bk / 49;
    const float4 pr = ((const float4*)params)[bk];
    const float th = pr.x, tw = pr.y, tx = pr.z, ty = pr.w;

    for (int idx = threadIdx.x; idx < 3072; idx += 256) {
        const int c  = idx >> 10;
        const int gy = (idx >> 5) & 31;
        const int gx = idx & 31;
        float xb = (2.f * gx + 1.f) / 32.f - 1.f;
        float yb = (2.f * gy + 1.f) / 32.f - 1.f;
        float ixn = fmaf(tw, xb, ty);
        float iyn = fmaf(th, yb, tx);
        float px = ((ixn + 1.f) * 128.f - 1.f) * 0.5f;
        float py = ((iyn + 1.f) * 128.f - 1.f) * 0.5f;
        float x0f = floorf(px), y0f = floorf(py);
        float wx = px - x0f, wy = py - y0f;
        int x0 = (int)x0f, y0 = (int)y0f;
        const float* im = img + ((size_t)b * 3 + c) * 16384;
        float v00 = tap(im, y0, x0);
        float v01 = tap(im, y0, x0 + 1);
        float v10 = tap(im, y0 + 1, x0);
        float v11 = tap(im, y0 + 1, x0 + 1);
        float r = v00 * (1.f - wy) * (1.f - wx) + v01 * (1.f - wy) * wx +
                  v10 * wy * (1.f - wx)        + v11 * wy * wx;
        out[(size_t)bk * 3072 + idx] = r;
    }
}

// ---------------------------------------------------------------- launch
extern "C" void kernel_launch(void* const* d_in, const int* in_sizes, int n_in,
                              void* d_out, int out_size, void* d_ws, size_t ws_size,
                              hipStream_t stream)
{
    const float* img       = (const float*)d_in[0];
    const float* eps_scale = (const float*)d_in[1];
    const float* eps_shift = (const float*)d_in[2];
    const float* w1 = (const float*)d_in[3],  *b1 = (const float*)d_in[4];
    const float* g1 = (const float*)d_in[5],  *be1 = (const float*)d_in[6];
    const float* w2 = (const float*)d_in[7],  *b2 = (const float*)d_in[8];
    const float* g2 = (const float*)d_in[9],  *be2 = (const float*)d_in[10];
    const float* w3 = (const float*)d_in[11], *b3 = (const float*)d_in[12];
    const float* g3 = (const float*)d_in[13], *be3 = (const float*)d_in[14];
    const float* w4 = (const float*)d_in[15], *b4 = (const float*)d_in[16];
    const float* g4 = (const float*)d_in[17], *be4 = (const float*)d_in[18];
    const float* wp = (const float*)d_in[19], *bp = (const float*)d_in[20];
    const float* wz = (const float*)d_in[21], *bz = (const float*)d_in[22];

    float* ws     = (float*)d_ws;
    float* stats  = ws;               // 512 floats: 4 layers x 64ch x {sum, sumsq}
    float* params = ws + 512;         // 32*49*4
    float* h1     = ws + 6784;                      // raw conv1 out: 32*64*63*63
    float* h2     = h1 + (size_t)32 * 64 * 63 * 63; // raw conv2 out
    float* h3     = h2 + (size_t)32 * 64 * 31 * 31; // raw conv3 out
    float* h4     = h3 + (size_t)32 * 64 * 15 * 15; // raw conv4 out

    float* outp = (float*)d_out;

    hipMemsetAsync(stats, 0, 512 * sizeof(float), stream);

    // conv1: 3->64, 128x128 -> 63x63, no input BN
    conv_kernel<3, 128, 128, 63, 63, 4, 256, 3, false>
        <<<dim3(32, 8, 16), 256, 0, stream>>>(img, w1, b1, nullptr, nullptr, nullptr, h1, stats + 0);
    // conv2: 64->64, 63x63 -> 31x31, applies bn1+elu while staging h1
    conv_kernel<64, 63, 63, 31, 31, 8, 256, 8, true>
        <<<dim3(32, 8, 4), 256, 0, stream>>>(h1, w2, b2, stats + 0, g1, be1, h2, stats + 128);
    // conv3: 64->64, 31x31 -> 15x15
    conv_kernel<64, 31, 31, 15, 15, 8, 128, 8, true>
        <<<dim3(32, 8, 2), 128, 0, stream>>>(h2, w3, b3, stats + 128, g2, be2, h3, stats + 256);
    // conv4: 64->64, 15x15 -> 7x7
    conv_kernel<64, 15, 15, 7, 7, 7, 64, 8, true>
        <<<dim3(32, 8, 1), 64, 0, stream>>>(h3, w4, b4, stats + 256, g3, be3, h4, stats + 384);

    head_kernel<<<32, 256, 0, stream>>>(h4, stats + 384, g4, be4, wp, bp, wz, bz,
                                        eps_scale, eps_shift, params);

    sampler_kernel<<<1568, 256, 0, stream>>>(img, params, outp);
}

// Round 6
// 232.922 us; speedup vs baseline: 2.5003x; 2.5003x over previous
//
#include <hip/hip_runtime.h>
#include <math.h>

#define BATCH 32

// ---------------------------------------------------------------- utilities
__device__ __forceinline__ float eluf(float v) { return v > 0.f ? v : expm1f(v); }
__device__ __forceinline__ float softplusf(float x) {
    return fmaxf(x, 0.f) + log1pf(expf(-fabsf(x)));
}
__device__ __forceinline__ float sigmoidf(float x) { return 1.f / (1.f + expf(-x)); }

// ---------------------------------------------------------------- conv 3x3 stride 2 (VALID)
// Direct-load design (no LDS tile). Thread = 2 vertically-adjacent output rows x 8 co:
// 15 independent loads (5 rows x 3 cols) feed 144 FMAs per ci (9.6 FMA/load).
// Weights are block-uniform -> scalar loads. launch_bounds(_,4) caps VGPR at 128
// so patch+accumulators stay live (R1 regression: VGPR=16 serialized load->use).
// Epilogue: per-channel sum/sumsq of raw output -> stats (atomics).
template <int CIN, int HIN, int WIN, int HOUT, int WOUT, int PAIRS, int BLOCK>
__global__ __launch_bounds__(BLOCK, 4) void conv_kernel(
    const float* __restrict__ in, const float* __restrict__ w, const float* __restrict__ bias,
    float* __restrict__ out, float* __restrict__ stats)
{
    constexpr int NW = BLOCK / 64;
    __shared__ float red_s[NW][8];
    __shared__ float red_q[NW][8];

    const int b   = blockIdx.x;
    const int co0 = blockIdx.y * 8;
    const int t   = threadIdx.x;

    const int xw_r  = t % WOUT;          // one div per thread (magic-mul, const WOUT)
    const int pr_r  = t / WOUT;
    const bool active = pr_r < PAIRS;    // all z-tiles are exact for our shapes
    const int pr = active ? pr_r : 0;
    const int xw = active ? xw_r : 0;
    const int y0 = (blockIdx.z * PAIRS + pr) * 2;   // output rows y0, y0+1
    const bool row1 = (y0 + 1) < HOUT;

    // clamped input-row offsets (rows 2*y0 .. 2*y0+4)
    int roff[5];
#pragma unroll
    for (int r = 0; r < 5; ++r)
        roff[r] = min(2 * y0 + r, HIN - 1) * WIN + 2 * xw;

    const float* ib = in + (size_t)b * CIN * HIN * WIN;

    float acc0[8], acc1[8];
#pragma unroll
    for (int u = 0; u < 8; ++u) { acc0[u] = bias[co0 + u]; acc1[u] = bias[co0 + u]; }

#pragma unroll 2
    for (int ci = 0; ci < CIN; ++ci) {
        const float* ip = ib + (size_t)ci * (HIN * WIN);
        float pch[15];                    // 15 independent loads -> all in flight
#pragma unroll
        for (int r = 0; r < 5; ++r)
#pragma unroll
            for (int c = 0; c < 3; ++c)
                pch[r * 3 + c] = ip[roff[r] + c];

        const float* wc = w + ((size_t)co0 * CIN + ci) * 9;
#pragma unroll
        for (int u = 0; u < 8; ++u)
#pragma unroll
            for (int j = 0; j < 9; ++j) {
                const float wv = wc[u * CIN * 9 + j];   // uniform -> SGPR
                acc0[u] = fmaf(pch[j],     wv, acc0[u]);
                acc1[u] = fmaf(pch[6 + j], wv, acc1[u]);
            }
    }

    // ---- write raw output + per-channel stats
    const int lane = t & 63, wv_ = t >> 6;
#pragma unroll
    for (int u = 0; u < 8; ++u) {
        float v0 = active ? acc0[u] : 0.f;
        float v1 = (active && row1) ? acc1[u] : 0.f;
        if (active) {
            float* op = out + (((size_t)b * 64 + co0 + u) * HOUT + y0) * WOUT + xw;
            op[0] = v0;
            if (row1) op[WOUT] = v1;
        }
        float s = v0 + v1, q = v0 * v0 + v1 * v1;
#pragma unroll
        for (int off = 32; off > 0; off >>= 1) {
            s += __shfl_down(s, off);
            q += __shfl_down(q, off);
        }
        if (lane == 0) { red_s[wv_][u] = s; red_q[wv_][u] = q; }
    }
    __syncthreads();
    if (t < 16) {
        const int u = t >> 1, which = t & 1;
        float tt = 0.f;
#pragma unroll
        for (int k = 0; k < NW; ++k) tt += which ? red_q[k][u] : red_s[k][u];
        atomicAdd(&stats[2 * (co0 + u) + which], tt);
    }
}

// ---------------------------------------------------------------- bn + elu (in place)
// memory-bound; scalar fp32 loads are fully coalesced (4B/lane). One div (magic-mul).
template <int PLANE>
__global__ __launch_bounds__(256) void bnelu_kernel(
    float* __restrict__ h, const float* __restrict__ stats,
    const float* __restrict__ g, const float* __restrict__ be)
{
    const float invN = 1.f / (float)(BATCH * PLANE);
    const long long total = (long long)BATCH * 64 * PLANE;
    for (long long idx = (long long)blockIdx.x * blockDim.x + threadIdx.x; idx < total;
         idx += (long long)gridDim.x * blockDim.x) {
        int c = (int)((idx / PLANE) & 63);
        float s = stats[2 * c], q = stats[2 * c + 1];
        float m = s * invN;
        float var = fmaf(q, invN, -m * m);
        float a = g[c] * rsqrtf(var + 1e-5f);
        float bb = fmaf(-a, m, be[c]);
        h[idx] = eluf(fmaf(a, h[idx], bb));
    }
}

// ---------------------------------------------------------------- head: bnelu(h4) + 1x1 convs + params
__global__ __launch_bounds__(256) void head_kernel(
    const float* __restrict__ x4, const float* __restrict__ stats4,
    const float* __restrict__ g4, const float* __restrict__ be4,
    const float* __restrict__ wp, const float* __restrict__ bp,
    const float* __restrict__ wz, const float* __restrict__ bz,
    const float* __restrict__ eps_scale, const float* __restrict__ eps_shift,
    float* __restrict__ params)
{
    __shared__ float xs[64 * 49];
    __shared__ float fe[64 * 49];
    __shared__ float zz[11 * 49];
    __shared__ float ha[64], hb[64];
    const int b = blockIdx.x, t = threadIdx.x;

    if (t < 64) {
        constexpr float invN = 1.f / (float)(BATCH * 49);
        float s = stats4[2 * t], q = stats4[2 * t + 1];
        float m = s * invN;
        float var = fmaf(q, invN, -m * m);
        float a = g4[t] * rsqrtf(var + 1e-5f);
        ha[t] = a;
        hb[t] = fmaf(-a, m, be4[t]);
    }
    __syncthreads();

    for (int i = t; i < 64 * 49; i += 256) {
        int c = i / 49;
        xs[i] = eluf(fmaf(ha[c], x4[(size_t)b * 64 * 49 + i], hb[c]));
    }
    __syncthreads();

    for (int i = t; i < 64 * 49; i += 256) {
        int co = i / 49, p = i % 49;
        float a = bp[co];
        for (int ci = 0; ci < 64; ++ci) a = fmaf(xs[ci * 49 + p], wp[co * 64 + ci], a);
        fe[i] = eluf(a);
    }
    __syncthreads();

    for (int i = t; i < 11 * 49; i += 256) {
        int co = i / 49, p = i % 49;
        float a = bz[co];
        for (int ci = 0; ci < 64; ++ci) a = fmaf(fe[ci * 49 + p], wz[co * 64 + ci], a);
        zz[i] = a;
    }
    __syncthreads();

    if (t < 49) {
        const int i = t / 7, j = t % 7;
        float es0 = eps_scale[((size_t)b * 49 + t) * 2 + 0];
        float es1 = eps_scale[((size_t)b * 49 + t) * 2 + 1];
        float eh0 = eps_shift[((size_t)b * 49 + t) * 2 + 0];
        float eh1 = eps_shift[((size_t)b * 49 + t) * 2 + 1];
        float zs0 = zz[3 * 49 + t] + softplusf(zz[5 * 49 + t]) * es0;
        float zs1 = zz[4 * 49 + t] + softplusf(zz[6 * 49 + t]) * es1;
        float zh0 = zz[7 * 49 + t] + softplusf(zz[9 * 49 + t]) * eh0;
        float zh1 = zz[8 * 49 + t] + softplusf(zz[10 * 49 + t]) * eh1;
        float th = sigmoidf(zs0) * 0.25f;
        float tw = sigmoidf(zs1) * 0.25f;
        float tx = ((float)i / 7.0f + sigmoidf(zh0) / 7.0f) * 2.f - 1.f;
        float ty = ((float)j / 7.0f + sigmoidf(zh1) / 7.0f) * 2.f - 1.f;
        float4* pp = (float4*)params;
        pp[b * 49 + t] = make_float4(th, tw, tx, ty);
    }
}

// ---------------------------------------------------------------- bilinear glimpse sampler
__device__ __forceinline__ float tap(const float* __restrict__ im, int yy, int xx) {
    bool ok = (xx >= 0) & (xx < 128) & (yy >= 0) & (yy < 128);
    int yc = min(max(yy, 0), 127);
    int xc = min(max(xx, 0), 127);
    return ok ? im[yc * 128 + xc] : 0.f;
}

__global__ __launch_bounds__(256) void sampler_kernel(
    const float* __restrict__ img, const float* __restrict__ params,
    float* __restrict__ out)
{
    const int bk = blockIdx.x;       // b*49 + k
    const int b  = bk / 49;
    const float4 pr = ((const float4*)params)[bk];
    const float th = pr.x, tw = pr.y, tx = pr.z, ty = pr.w;

    for (int idx = threadIdx.x; idx < 3072; idx += 256) {
        const int c  = idx >> 10;
        const int gy = (idx >> 5) & 31;
        const int gx = idx & 31;
        float xb = (2.f * gx + 1.f) / 32.f - 1.f;
        float yb = (2.f * gy + 1.f) / 32.f - 1.f;
        float ixn = fmaf(tw, xb, ty);
        float iyn = fmaf(th, yb, tx);
        float px = ((ixn + 1.f) * 128.f - 1.f) * 0.5f;
        float py = ((iyn + 1.f) * 128.f - 1.f) * 0.5f;
        float x0f = floorf(px), y0f = floorf(py);
        float wx = px - x0f, wy = py - y0f;
        int x0 = (int)x0f, y0 = (int)y0f;
        const float* im = img + ((size_t)b * 3 + c) * 16384;
        float v00 = tap(im, y0, x0);
        float v01 = tap(im, y0, x0 + 1);
        float v10 = tap(im, y0 + 1, x0);
        float v11 = tap(im, y0 + 1, x0 + 1);
        float r = v00 * (1.f - wy) * (1.f - wx) + v01 * (1.f - wy) * wx +
                  v10 * wy * (1.f - wx)        + v11 * wy * wx;
        out[(size_t)bk * 3072 + idx] = r;
    }
}

// ---------------------------------------------------------------- launch
extern "C" void kernel_launch(void* const* d_in, const int* in_sizes, int n_in,
                              void* d_out, int out_size, void* d_ws, size_t ws_size,
                              hipStream_t stream)
{
    const float* img       = (const float*)d_in[0];
    const float* eps_scale = (const float*)d_in[1];
    const float* eps_shift = (const float*)d_in[2];
    const float* w1 = (const float*)d_in[3],  *b1 = (const float*)d_in[4];
    const float* g1 = (const float*)d_in[5],  *be1 = (const float*)d_in[6];
    const float* w2 = (const float*)d_in[7],  *b2 = (const float*)d_in[8];
    const float* g2 = (const float*)d_in[9],  *be2 = (const float*)d_in[10];
    const float* w3 = (const float*)d_in[11], *b3 = (const float*)d_in[12];
    const float* g3 = (const float*)d_in[13], *be3 = (const float*)d_in[14];
    const float* w4 = (const float*)d_in[15], *b4 = (const float*)d_in[16];
    const float* g4 = (const float*)d_in[17], *be4 = (const float*)d_in[18];
    const float* wp = (const float*)d_in[19], *bp = (const float*)d_in[20];
    const float* wz = (const float*)d_in[21], *bz = (const float*)d_in[22];

    float* ws     = (float*)d_ws;
    float* stats  = ws;               // 512 floats: 4 layers x 64ch x {sum, sumsq}
    float* params = ws + 512;         // 32*49*4
    float* h1     = ws + 6784;                      // 32*64*63*63
    float* h2     = h1 + (size_t)32 * 64 * 63 * 63; // 32*64*31*31
    float* h3     = h2 + (size_t)32 * 64 * 31 * 31; // 32*64*15*15
    float* h4     = h3 + (size_t)32 * 64 * 15 * 15; // 32*64*7*7

    float* outp = (float*)d_out;

    hipMemsetAsync(stats, 0, 512 * sizeof(float), stream);

    // conv1: 3->64, 128x128 -> 63x63  (32 row-pairs: PAIRS=4, z=8)
    conv_kernel<3, 128, 128, 63, 63, 4, 256>
        <<<dim3(32, 8, 8), 256, 0, stream>>>(img, w1, b1, h1, stats + 0);
    bnelu_kernel<63 * 63><<<2048, 256, 0, stream>>>(h1, stats + 0, g1, be1);

    // conv2: 64->64, 63x63 -> 31x31  (16 row-pairs: PAIRS=8, z=2)
    conv_kernel<64, 63, 63, 31, 31, 8, 256>
        <<<dim3(32, 8, 2), 256, 0, stream>>>(h1, w2, b2, h2, stats + 128);
    bnelu_kernel<31 * 31><<<2048, 256, 0, stream>>>(h2, stats + 128, g2, be2);

    // conv3: 64->64, 31x31 -> 15x15  (8 row-pairs: PAIRS=8, z=1, block 128)
    conv_kernel<64, 31, 31, 15, 15, 8, 128>
        <<<dim3(32, 8, 1), 128, 0, stream>>>(h2, w3, b3, h3, stats + 256);
    bnelu_kernel<15 * 15><<<1024, 256, 0, stream>>>(h3, stats + 256, g3, be3);

    // conv4: 64->64, 15x15 -> 7x7  (4 row-pairs: PAIRS=4, z=1, block 64)
    conv_kernel<64, 15, 15, 7, 7, 4, 64>
        <<<dim3(32, 8, 1), 64, 0, stream>>>(h3, w4, b4, h4, stats + 384);

    // head fuses bn4+elu; h4 stays raw
    head_kernel<<<32, 256, 0, stream>>>(h4, stats + 384, g4, be4, wp, bp, wz, bz,
                                        eps_scale, eps_shift, params);

    sampler_kernel<<<1568, 256, 0, stream>>>(img, params, outp);
}

// Round 7
// 205.040 us; speedup vs baseline: 2.8404x; 1.1360x over previous
//
#include <hip/hip_runtime.h>
#include <math.h>

#define BATCH 32

// ---------------------------------------------------------------- utilities
__device__ __forceinline__ float eluf(float v) { return v > 0.f ? v : expm1f(v); }
__device__ __forceinline__ float softplusf(float x) {
    return fmaxf(x, 0.f) + log1pf(expf(-fabsf(x)));
}
__device__ __forceinline__ float sigmoidf(float x) { return 1.f / (1.f + expf(-x)); }

// ---------------------------------------------------------------- conv 3x3 stride 2 (VALID)
// Occupancy-first design: thread = 1 output px x G output channels, direct global
// loads (L1/L2-served). G chosen per layer so the grid is >=16-32 waves/CU
// (R6 lesson: 8 waves/CU -> 21% occupancy -> latency-bound at 28% VALUBusy).
// launch_bounds(_,8) caps VGPR at 64 so 8 waves/SIMD stay resident; thread state
// (9 patch + G acc + addr) fits. Weights are block-uniform -> scalar loads.
// Epilogue: per-channel sum/sumsq of raw output -> stats (atomics).
template <int CIN, int HIN, int WIN, int HOUT, int WOUT, int G, int BLOCK>
__global__ __launch_bounds__(BLOCK, 8) void conv_kernel(
    const float* __restrict__ in, const float* __restrict__ w, const float* __restrict__ bias,
    float* __restrict__ out, float* __restrict__ stats)
{
    constexpr int NW = BLOCK / 64;
    __shared__ float red_s[NW][G];
    __shared__ float red_q[NW][G];

    const int b   = blockIdx.x;
    const int co0 = blockIdx.y * G;
    const int t   = threadIdx.x;
    const int px  = blockIdx.z * BLOCK + t;
    const bool active = px < HOUT * WOUT;
    const int p = active ? px : 0;
    const int y = p / WOUT, x = p % WOUT;

    const float* ib = in + (size_t)b * CIN * HIN * WIN + (2 * y) * WIN + 2 * x;

    float acc[G];
#pragma unroll
    for (int u = 0; u < G; ++u) acc[u] = bias[co0 + u];

#pragma unroll 2
    for (int ci = 0; ci < CIN; ++ci) {
        const float* ip = ib + (size_t)ci * (HIN * WIN);
        float pch[9];                       // 9 independent loads in flight
#pragma unroll
        for (int ky = 0; ky < 3; ++ky)
#pragma unroll
            for (int kx = 0; kx < 3; ++kx)
                pch[ky * 3 + kx] = ip[ky * WIN + kx];

        const float* wc = w + ((size_t)co0 * CIN + ci) * 9;   // uniform -> SGPR
#pragma unroll
        for (int u = 0; u < G; ++u)
#pragma unroll
            for (int j = 0; j < 9; ++j)
                acc[u] = fmaf(pch[j], wc[u * CIN * 9 + j], acc[u]);
    }

    // ---- write raw output + per-channel stats
    const int lane = t & 63, wv_ = t >> 6;
#pragma unroll
    for (int u = 0; u < G; ++u) {
        float v = active ? acc[u] : 0.f;
        if (active)
            out[(((size_t)b * 64 + co0 + u) * HOUT + y) * WOUT + x] = v;
        float s = v, q = v * v;
#pragma unroll
        for (int off = 32; off > 0; off >>= 1) {
            s += __shfl_down(s, off);
            q += __shfl_down(q, off);
        }
        if (lane == 0) { red_s[wv_][u] = s; red_q[wv_][u] = q; }
    }
    __syncthreads();
    if (t < 2 * G) {
        const int u = t >> 1, which = t & 1;
        float tt = 0.f;
#pragma unroll
        for (int k = 0; k < NW; ++k) tt += which ? red_q[k][u] : red_s[k][u];
        atomicAdd(&stats[2 * (co0 + u) + which], tt);
    }
}

// ---------------------------------------------------------------- bn + elu (in place)
template <int PLANE>
__global__ __launch_bounds__(256) void bnelu_kernel(
    float* __restrict__ h, const float* __restrict__ stats,
    const float* __restrict__ g, const float* __restrict__ be)
{
    const float invN = 1.f / (float)(BATCH * PLANE);
    const long long total = (long long)BATCH * 64 * PLANE;
    for (long long idx = (long long)blockIdx.x * blockDim.x + threadIdx.x; idx < total;
         idx += (long long)gridDim.x * blockDim.x) {
        int c = (int)((idx / PLANE) & 63);
        float s = stats[2 * c], q = stats[2 * c + 1];
        float m = s * invN;
        float var = fmaf(q, invN, -m * m);
        float a = g[c] * rsqrtf(var + 1e-5f);
        float bb = fmaf(-a, m, be[c]);
        h[idx] = eluf(fmaf(a, h[idx], bb));
    }
}

// ---------------------------------------------------------------- head: bnelu(h4) + 1x1 convs + params
__global__ __launch_bounds__(256) void head_kernel(
    const float* __restrict__ x4, const float* __restrict__ stats4,
    const float* __restrict__ g4, const float* __restrict__ be4,
    const float* __restrict__ wp, const float* __restrict__ bp,
    const float* __restrict__ wz, const float* __restrict__ bz,
    const float* __restrict__ eps_scale, const float* __restrict__ eps_shift,
    float* __restrict__ params)
{
    __shared__ float xs[64 * 49];
    __shared__ float fe[64 * 49];
    __shared__ float zz[11 * 49];
    __shared__ float ha[64], hb[64];
    const int b = blockIdx.x, t = threadIdx.x;

    if (t < 64) {
        constexpr float invN = 1.f / (float)(BATCH * 49);
        float s = stats4[2 * t], q = stats4[2 * t + 1];
        float m = s * invN;
        float var = fmaf(q, invN, -m * m);
        float a = g4[t] * rsqrtf(var + 1e-5f);
        ha[t] = a;
        hb[t] = fmaf(-a, m, be4[t]);
    }
    __syncthreads();

    for (int i = t; i < 64 * 49; i += 256) {
        int c = i / 49;
        xs[i] = eluf(fmaf(ha[c], x4[(size_t)b * 64 * 49 + i], hb[c]));
    }
    __syncthreads();

    for (int i = t; i < 64 * 49; i += 256) {
        int co = i / 49, p = i % 49;
        float a = bp[co];
        for (int ci = 0; ci < 64; ++ci) a = fmaf(xs[ci * 49 + p], wp[co * 64 + ci], a);
        fe[i] = eluf(a);
    }
    __syncthreads();

    for (int i = t; i < 11 * 49; i += 256) {
        int co = i / 49, p = i % 49;
        float a = bz[co];
        for (int ci = 0; ci < 64; ++ci) a = fmaf(fe[ci * 49 + p], wz[co * 64 + ci], a);
        zz[i] = a;
    }
    __syncthreads();

    if (t < 49) {
        const int i = t / 7, j = t % 7;
        float es0 = eps_scale[((size_t)b * 49 + t) * 2 + 0];
        float es1 = eps_scale[((size_t)b * 49 + t) * 2 + 1];
        float eh0 = eps_shift[((size_t)b * 49 + t) * 2 + 0];
        float eh1 = eps_shift[((size_t)b * 49 + t) * 2 + 1];
        float zs0 = zz[3 * 49 + t] + softplusf(zz[5 * 49 + t]) * es0;
        float zs1 = zz[4 * 49 + t] + softplusf(zz[6 * 49 + t]) * es1;
        float zh0 = zz[7 * 49 + t] + softplusf(zz[9 * 49 + t]) * eh0;
        float zh1 = zz[8 * 49 + t] + softplusf(zz[10 * 49 + t]) * eh1;
        float th = sigmoidf(zs0) * 0.25f;
        float tw = sigmoidf(zs1) * 0.25f;
        float tx = ((float)i / 7.0f + sigmoidf(zh0) / 7.0f) * 2.f - 1.f;
        float ty = ((float)j / 7.0f + sigmoidf(zh1) / 7.0f) * 2.f - 1.f;
        float4* pp = (float4*)params;
        pp[b * 49 + t] = make_float4(th, tw, tx, ty);
    }
}

// ---------------------------------------------------------------- bilinear glimpse sampler
__device__ __forceinline__ float tap(const float* __restrict__ im, int yy, int xx) {
    bool ok = (xx >= 0) & (xx < 128) & (yy >= 0) & (yy < 128);
    int yc = min(max(yy, 0), 127);
    int xc = min(max(xx, 0), 127);
    return ok ? im[yc * 128 + xc] : 0.f;
}

__global__ __launch_bounds__(256) void sampler_kernel(
    const float* __restrict__ img, const float* __restrict__ params,
    float* __restrict__ out)
{
    const int bk = blockIdx.x;       // b*49 + k
    const int b  = bk / 49;
    const float4 pr = ((const float4*)params)[bk];
    const float th = pr.x, tw = pr.y, tx = pr.z, ty = pr.w;

    for (int idx = threadIdx.x; idx < 3072; idx += 256) {
        const int c  = idx >> 10;
        const int gy = (idx >> 5) & 31;
        const int gx = idx & 31;
        float xb = (2.f * gx + 1.f) / 32.f - 1.f;
        float yb = (2.f * gy + 1.f) / 32.f - 1.f;
        float ixn = fmaf(tw, xb, ty);
        float iyn = fmaf(th, yb, tx);
        float px = ((ixn + 1.f) * 128.f - 1.f) * 0.5f;
        float py = ((iyn + 1.f) * 128.f - 1.f) * 0.5f;
        float x0f = floorf(px), y0f = floorf(py);
        float wx = px - x0f, wy = py - y0f;
        int x0 = (int)x0f, y0 = (int)y0f;
        const float* im = img + ((size_t)b * 3 + c) * 16384;
        float v00 = tap(im, y0, x0);
        float v01 = tap(im, y0, x0 + 1);
        float v10 = tap(im, y0 + 1, x0);
        float v11 = tap(im, y0 + 1, x0 + 1);
        float r = v00 * (1.f - wy) * (1.f - wx) + v01 * (1.f - wy) * wx +
                  v10 * wy * (1.f - wx)        + v11 * wy * wx;
        out[(size_t)bk * 3072 + idx] = r;
    }
}

// ---------------------------------------------------------------- launch
extern "C" void kernel_launch(void* const* d_in, const int* in_sizes, int n_in,
                              void* d_out, int out_size, void* d_ws, size_t ws_size,
                              hipStream_t stream)
{
    const float* img       = (const float*)d_in[0];
    const float* eps_scale = (const float*)d_in[1];
    const float* eps_shift = (const float*)d_in[2];
    const float* w1 = (const float*)d_in[3],  *b1 = (const float*)d_in[4];
    const float* g1 = (const float*)d_in[5],  *be1 = (const float*)d_in[6];
    const float* w2 = (const float*)d_in[7],  *b2 = (const float*)d_in[8];
    const float* g2 = (const float*)d_in[9],  *be2 = (const float*)d_in[10];
    const float* w3 = (const float*)d_in[11], *b3 = (const float*)d_in[12];
    const float* g3 = (const float*)d_in[13], *be3 = (const float*)d_in[14];
    const float* w4 = (const float*)d_in[15], *b4 = (const float*)d_in[16];
    const float* g4 = (const float*)d_in[17], *be4 = (const float*)d_in[18];
    const float* wp = (const float*)d_in[19], *bp = (const float*)d_in[20];
    const float* wz = (const float*)d_in[21], *bz = (const float*)d_in[22];

    float* ws     = (float*)d_ws;
    float* stats  = ws;               // 512 floats: 4 layers x 64ch x {sum, sumsq}
    float* params = ws + 512;         // 32*49*4
    float* h1     = ws + 6784;                      // 32*64*63*63
    float* h2     = h1 + (size_t)32 * 64 * 63 * 63; // 32*64*31*31
    float* h3     = h2 + (size_t)32 * 64 * 31 * 31; // 32*64*15*15
    float* h4     = h3 + (size_t)32 * 64 * 15 * 15; // 32*64*7*7

    float* outp = (float*)d_out;

    hipMemsetAsync(stats, 0, 512 * sizeof(float), stream);

    // conv1: 3->64, 128x128 -> 63x63.  G=8: 4096 blocks = 16k waves (CU-saturated)
    conv_kernel<3, 128, 128, 63, 63, 8, 256>
        <<<dim3(32, 8, 16), 256, 0, stream>>>(img, w1, b1, h1, stats + 0);
    bnelu_kernel<63 * 63><<<2048, 256, 0, stream>>>(h1, stats + 0, g1, be1);

    // conv2: 64->64, 63x63 -> 31x31.  G=4: 2048 blocks = 8192 waves = 32/CU
    conv_kernel<64, 63, 63, 31, 31, 4, 256>
        <<<dim3(32, 16, 4), 256, 0, stream>>>(h1, w2, b2, h2, stats + 128);
    bnelu_kernel<31 * 31><<<2048, 256, 0, stream>>>(h2, stats + 128, g2, be2);

    // conv3: 64->64, 31x31 -> 15x15.  G=2: 1024 blocks = 4096 waves = 16/CU
    conv_kernel<64, 31, 31, 15, 15, 2, 256>
        <<<dim3(32, 32, 1), 256, 0, stream>>>(h2, w3, b3, h3, stats + 256);
    bnelu_kernel<15 * 15><<<1024, 256, 0, stream>>>(h3, stats + 256, g3, be3);

    // conv4: 64->64, 15x15 -> 7x7.  G=1: 2048 blocks (64 thr) = 2048 waves = 8/CU
    conv_kernel<64, 15, 15, 7, 7, 1, 64>
        <<<dim3(32, 64, 1), 64, 0, stream>>>(h3, w4, b4, h4, stats + 384);

    // head fuses bn4+elu; h4 stays raw
    head_kernel<<<32, 256, 0, stream>>>(h4, stats + 384, g4, be4, wp, bp, wz, bz,
                                        eps_scale, eps_shift, params);

    sampler_kernel<<<1568, 256, 0, stream>>>(img, params, outp);
}